// Round 3
// baseline (490.948 us; speedup 1.0000x reference)
//
#include <hip/hip_runtime.h>
#include <math.h>

// Problem constants
#define BATCH 8
#define CIN 512
#define H 128
#define W 128
#define COUT 3
#define CHUNKS 16
#define CH (CIN / CHUNKS)          // 32 channels per block
#define R 8                        // output rows per wave
#define NROWS (R + 2)              // input rows per wave (halo)
#define BLOCK_ROWS 16              // 2 row-strips of 8
#define TILES_Y (H / BLOCK_ROWS)   // 8
#define HWP (H * W)

// ---- per-channel prefetch: 10 main rows (1 col/lane) + packed halo ----
__device__ __forceinline__ void pf(float (&v)[NROWS], float& hp,
                                   const float* __restrict__ chan,
                                   const int (&goff)[NROWS], int colOff, int hoff)
{
#pragma unroll
    for (int r = 0; r < NROWS; r++)
        v[r] = chan[goff[r] + colOff];
    hp = chan[hoff];
}

// ---- per-channel compute: 8 rows x 1 col x 3 cout ----
__device__ __forceinline__ void compute_ch(
    const float (&v)[NROWS], float hp, const float* __restrict__ wp,
    float (&acc)[R * 3], int lane, float m0, float m9, float lex, float rex)
{
    float wv[27];
#pragma unroll
    for (int co = 0; co < 3; co++)
#pragma unroll
        for (int k = 0; k < 9; k++)
            wv[co * 9 + k] = wp[co * (CIN * 9) + k];   // wave-uniform -> s_load

    float wl[3], wm[3], wr[3];
#pragma unroll
    for (int rr = 0; rr < NROWS; rr++) {
        const int s = rr % 3;
        float mrow = (rr == 0) ? m0 : ((rr == NROWS - 1) ? m9 : 1.f);
        float mv = v[rr] * mrow;
        float hL = __shfl(hp, 2 * rr)     * (mrow * lex);
        float hR = __shfl(hp, 2 * rr + 1) * (mrow * rex);
        float lf = __shfl_up(mv, 1);
        float rg = __shfl_down(mv, 1);
        wl[s] = (lane == 0)  ? hL : lf;
        wm[s] = mv;
        wr[s] = (lane == 63) ? hR : rg;

        if (rr >= 2) {
            const int p  = rr - 2;
            const int s0 = p % 3, s1 = (p + 1) % 3, s2 = (p + 2) % 3;
#pragma unroll
            for (int co = 0; co < 3; co++) {
                const float* w = &wv[co * 9];
                float a = acc[p * 3 + co];
                a += wl[s0] * w[0] + wm[s0] * w[1] + wr[s0] * w[2];
                a += wl[s1] * w[3] + wm[s1] * w[4] + wr[s1] * w[5];
                a += wl[s2] * w[6] + wm[s2] * w[7] + wr[s2] * w[8];
                acc[p * 3 + co] = a;
            }
        }
    }
}

template <bool USE_WS>
__global__ __launch_bounds__(256) void torgb_conv(
    const float* __restrict__ in, const float* __restrict__ skip,
    const float* __restrict__ weight, const float* __restrict__ bias,
    float* __restrict__ out, float* __restrict__ ws)
{
    const int bx    = blockIdx.x;
    const int tile  = bx & (TILES_Y - 1);          // 0..7
    const int b     = (bx >> 3) & (BATCH - 1);     // 0..7
    const int chunk = bx >> 6;                     // 0..15
    const int ci0   = chunk * CH;

    const int tid  = threadIdx.x;
    const int lane = tid & 63;
    const int wave = tid >> 6;
    const int rs   = wave >> 1;                    // row strip 0/1
    const int chq  = wave & 1;                     // col half 0/1
    const int cw   = chq * 64;                     // wave's first column
    const int yb   = tile * BLOCK_ROWS + rs * R;   // first output row
    const int colOff = cw + lane;

    // wave-uniform clamped row offsets
    int goff[NROWS];
#pragma unroll
    for (int r = 0; r < NROWS; r++) {
        int g = yb - 1 + r;
        int gc = g < 0 ? 0 : (g > H - 1 ? H - 1 : g);
        goff[r] = gc * W;
    }
    const float m0  = (yb >= 1) ? 1.f : 0.f;
    const float m9  = (yb + R <= H - 1) ? 1.f : 0.f;
    const float lex = (cw > 0) ? 1.f : 0.f;
    const float rex = (cw + 64 < W) ? 1.f : 0.f;

    // per-lane packed-halo offset: lane 2r -> (row r, col cw-1), 2r+1 -> (row r, col cw+64)
    int hoff;
    {
        int rr = lane >> 1; if (rr > NROWS - 1) rr = NROWS - 1;
        int side = lane & 1;
        int g = yb - 1 + rr; g = g < 0 ? 0 : (g > H - 1 ? H - 1 : g);
        int hcol = cw - 1 + 65 * side;
        hcol = hcol < 0 ? 0 : (hcol > W - 1 ? W - 1 : hcol);
        hoff = g * W + hcol;
    }

    float acc[R * 3];
#pragma unroll
    for (int i = 0; i < R * 3; i++) acc[i] = 0.f;

    const float* chan0 = in + ((size_t)b * CIN + ci0) * HWP;
    const float* wbase = weight + (size_t)ci0 * 9;

    float vA[NROWS], vB[NROWS], hA, hB;
    pf(vA, hA, chan0, goff, colOff, hoff);

#pragma unroll 2
    for (int ci = 0; ci < CH; ci += 2) {
        pf(vB, hB, chan0 + (size_t)(ci + 1) * HWP, goff, colOff, hoff);
        compute_ch(vA, hA, wbase + (size_t)ci * 9, acc, lane, m0, m9, lex, rex);
        if (ci + 2 < CH)
            pf(vA, hA, chan0 + (size_t)(ci + 2) * HWP, goff, colOff, hoff);
        compute_ch(vB, hB, wbase + (size_t)(ci + 1) * 9, acc, lane, m0, m9, lex, rex);
    }

    const float scale = 1.0f / sqrtf((float)(CIN * 9));

    if (USE_WS) {
        // plain coalesced partial stores: ws[((chunk*B + b)*3 + co)*HW + y*W + x]
        float* dst = ws + (((size_t)chunk * BATCH + b) * COUT) * HWP;
#pragma unroll
        for (int p = 0; p < R; p++) {
            int y = yb + p;
#pragma unroll
            for (int co = 0; co < 3; co++)
                dst[(size_t)co * HWP + y * W + colOff] = acc[p * 3 + co] * scale;
        }
    } else {
        float* outb = out + (size_t)b * COUT * HWP;
        const int x = colOff;
        int j0, j1; float wh0, wh1;
        if ((x & 1) == 0) { j0 = x >> 1;       wh0 = 0.75f; j1 = (x >> 1) - 1; wh1 = 0.25f; }
        else              { j0 = (x + 1) >> 1; wh0 = 0.25f; j1 = (x - 1) >> 1; wh1 = 0.75f; }
        const bool j0ok = (j0 >= 0 && j0 < 64), j1ok = (j1 >= 0 && j1 < 64);
#pragma unroll
        for (int p = 0; p < R; p++) {
            int y = yb + p;
            int i0, i1; float wv0, wv1;
            if ((y & 1) == 0) { i0 = y >> 1;       wv0 = 0.75f; i1 = (y >> 1) - 1; wv1 = 0.25f; }
            else              { i0 = (y + 1) >> 1; wv0 = 0.25f; i1 = (y - 1) >> 1; wv1 = 0.75f; }
            const bool i0ok = (i0 >= 0 && i0 < 64), i1ok = (i1 >= 0 && i1 < 64);
#pragma unroll
            for (int co = 0; co < 3; co++) {
                float vv = acc[p * 3 + co] * scale;
                if (chunk == 0) {
                    const float* sk = skip + (size_t)(b * COUT + co) * 64 * 64;
                    float s00 = (i0ok && j0ok) ? sk[i0 * 64 + j0] : 0.f;
                    float s01 = (i0ok && j1ok) ? sk[i0 * 64 + j1] : 0.f;
                    float s10 = (i1ok && j0ok) ? sk[i1 * 64 + j0] : 0.f;
                    float s11 = (i1ok && j1ok) ? sk[i1 * 64 + j1] : 0.f;
                    vv += bias[co] + wv0 * (wh0 * s00 + wh1 * s01)
                                   + wv1 * (wh0 * s10 + wh1 * s11);
                }
                atomicAdd(&outb[(size_t)co * HWP + y * W + x], vv);
            }
        }
    }
}

// ---- reduction: out = sum_c ws[c] + bias + upsampled skip ----
__global__ __launch_bounds__(256) void torgb_reduce(
    const float* __restrict__ ws, const float* __restrict__ skip,
    const float* __restrict__ bias, float* __restrict__ out)
{
    const int n4 = BATCH * COUT * HWP / 4;               // 98304
    int e4 = blockIdx.x * 256 + threadIdx.x;
    if (e4 >= n4) return;

    const int x4  = e4 & (W / 4 - 1);                    // 0..31
    const int y   = (e4 >> 5) & (H - 1);
    const int co  = (e4 >> 12) % COUT;
    const int b   = e4 / (COUT * H * W / 4);
    const int x0  = x4 * 4;

    float4 sum = make_float4(0.f, 0.f, 0.f, 0.f);
#pragma unroll
    for (int c = 0; c < CHUNKS; c++) {
        const float4 v = *(const float4*)&ws[((((size_t)c * BATCH + b) * COUT + co) * H + y) * W + x0];
        sum.x += v.x; sum.y += v.y; sum.z += v.z; sum.w += v.w;
    }

    // skip upsample (separable [.25 .75 .75 .25]) + bias
    int i0, i1; float wv0, wv1;
    if ((y & 1) == 0) { i0 = y >> 1;       wv0 = 0.75f; i1 = (y >> 1) - 1; wv1 = 0.25f; }
    else              { i0 = (y + 1) >> 1; wv0 = 0.25f; i1 = (y - 1) >> 1; wv1 = 0.75f; }
    const bool i0ok = (i0 >= 0 && i0 < 64), i1ok = (i1 >= 0 && i1 < 64);
    const float* sk = skip + (size_t)(b * COUT + co) * 64 * 64;
    const float bi = bias[co];

    float r[4] = {sum.x, sum.y, sum.z, sum.w};
#pragma unroll
    for (int q = 0; q < 4; q++) {
        int x = x0 + q;
        int j0, j1; float wh0, wh1;
        if ((x & 1) == 0) { j0 = x >> 1;       wh0 = 0.75f; j1 = (x >> 1) - 1; wh1 = 0.25f; }
        else              { j0 = (x + 1) >> 1; wh0 = 0.25f; j1 = (x - 1) >> 1; wh1 = 0.75f; }
        const bool j0ok = (j0 >= 0 && j0 < 64), j1ok = (j1 >= 0 && j1 < 64);
        float s00 = (i0ok && j0ok) ? sk[i0 * 64 + j0] : 0.f;
        float s01 = (i0ok && j1ok) ? sk[i0 * 64 + j1] : 0.f;
        float s10 = (i1ok && j0ok) ? sk[i1 * 64 + j0] : 0.f;
        float s11 = (i1ok && j1ok) ? sk[i1 * 64 + j1] : 0.f;
        r[q] += bi + wv0 * (wh0 * s00 + wh1 * s01) + wv1 * (wh0 * s10 + wh1 * s11);
    }
    *(float4*)&out[(size_t)e4 * 4] = make_float4(r[0], r[1], r[2], r[3]);
}

extern "C" void kernel_launch(void* const* d_in, const int* in_sizes, int n_in,
                              void* d_out, int out_size, void* d_ws, size_t ws_size,
                              hipStream_t stream) {
    const float* in     = (const float*)d_in[0];
    const float* skip   = (const float*)d_in[1];
    const float* weight = (const float*)d_in[2];
    const float* bias   = (const float*)d_in[3];
    float* out = (float*)d_out;
    float* ws  = (float*)d_ws;

    const size_t ws_needed = (size_t)CHUNKS * BATCH * COUT * HWP * sizeof(float);
    const dim3 grid(CHUNKS * BATCH * TILES_Y);   // 1024 blocks

    if (ws_size >= ws_needed) {
        torgb_conv<true><<<grid, 256, 0, stream>>>(in, skip, weight, bias, out, ws);
        const int n4 = BATCH * COUT * HWP / 4;
        torgb_reduce<<<(n4 + 255) / 256, 256, 0, stream>>>(ws, skip, bias, out);
    } else {
        hipMemsetAsync(out, 0, (size_t)out_size * sizeof(float), stream);
        torgb_conv<false><<<grid, 256, 0, stream>>>(in, skip, weight, bias, out, ws);
    }
}

// Round 4
// 376.297 us; speedup vs baseline: 1.3047x; 1.3047x over previous
//
#include <hip/hip_runtime.h>
#include <math.h>

// Problem constants
#define BATCH 8
#define CIN 512
#define H 128
#define W 128
#define COUT 3
#define CSPLIT 16
#define CH (CIN / CSPLIT)     // 32 channels per block
#define HWP (H * W)
#define YTILES 16             // blocks of 8 rows

__device__ __forceinline__ void loadrows(float4& v0, float4& v1, float4& v2,
                                         const float* __restrict__ p,
                                         int o0, int o1, int o2) {
    v0 = *(const float4*)(p + o0);
    v1 = *(const float4*)(p + o1);
    v2 = *(const float4*)(p + o2);
}

// one input channel's contribution to 3 couts x 4 x-positions
__device__ __forceinline__ void compute_ch(
    float4 v0, float4 v1, float4 v2,
    const float* __restrict__ wp,   // &weight[co=0][ci][0]; co stride CIN*9
    float (&acc)[COUT][4],
    float mt, float mb, float ml, float mr)
{
    float lw0 = __shfl_up(v0.w, 1),  rw0 = __shfl_down(v0.x, 1);
    float lw1 = __shfl_up(v1.w, 1),  rw1 = __shfl_down(v1.x, 1);
    float lw2 = __shfl_up(v2.w, 1),  rw2 = __shfl_down(v2.x, 1);
    // boundary masks (row 0 / row 2 vertical, lane-edge horizontal)
    v0.x *= mt; v0.y *= mt; v0.z *= mt; v0.w *= mt;
    v2.x *= mb; v2.y *= mb; v2.z *= mb; v2.w *= mb;
    lw0 *= mt * ml; lw1 *= ml; lw2 *= mb * ml;
    rw0 *= mt * mr; rw1 *= mr; rw2 *= mb * mr;
#pragma unroll
    for (int co = 0; co < COUT; co++) {
        const float* w = wp + co * (CIN * 9);   // wave-uniform -> s_load
        const float w0=w[0], w1=w[1], w2=w[2], w3=w[3], w4=w[4],
                    w5=w[5], w6=w[6], w7=w[7], w8=w[8];
        acc[co][0] += lw0 *w0 + v0.x*w1 + v0.y*w2
                    + lw1 *w3 + v1.x*w4 + v1.y*w5
                    + lw2 *w6 + v2.x*w7 + v2.y*w8;
        acc[co][1] += v0.x*w0 + v0.y*w1 + v0.z*w2
                    + v1.x*w3 + v1.y*w4 + v1.z*w5
                    + v2.x*w6 + v2.y*w7 + v2.z*w8;
        acc[co][2] += v0.y*w0 + v0.z*w1 + v0.w*w2
                    + v1.y*w3 + v1.z*w4 + v1.w*w5
                    + v2.y*w6 + v2.z*w7 + v2.w*w8;
        acc[co][3] += v0.z*w0 + v0.w*w1 + rw0 *w2
                    + v1.z*w3 + v1.w*w4 + rw1 *w5
                    + v2.z*w6 + v2.w*w7 + rw2 *w8;
    }
}

template <bool USE_WS>
__global__ __launch_bounds__(256, 4) void torgb_conv(
    const float* __restrict__ in, const float* __restrict__ skip,
    const float* __restrict__ weight, const float* __restrict__ bias,
    float* __restrict__ out, float* __restrict__ ws)
{
    const int bx    = blockIdx.x;
    const int ytile = bx & (YTILES - 1);
    const int b     = (bx >> 4) & (BATCH - 1);
    const int chunk = bx >> 7;                 // 0..15
    const int ci0   = chunk * CH;

    const int tid = threadIdx.x;
    const int xg  = tid & 31;       // x-group (4 floats)
    const int ry  = tid >> 5;       // 0..7
    const int y   = ytile * 8 + ry;
    const int x0  = xg * 4;

    const float mt = (y > 0)     ? 1.f : 0.f;
    const float mb = (y < H - 1) ? 1.f : 0.f;
    const float ml = (xg > 0)    ? 1.f : 0.f;
    const float mr = (xg < 31)   ? 1.f : 0.f;

    const int yc0 = (y > 0) ? y - 1 : 0;
    const int yc2 = (y < H - 1) ? y + 1 : H - 1;
    const int o0 = yc0 * W + x0, o1 = y * W + x0, o2 = yc2 * W + x0;

    const float* chan = in + ((size_t)b * CIN + ci0) * HWP;  // uniform, bumped per ch
    const float* wp   = weight + (size_t)ci0 * 9;

    float acc[COUT][4];
#pragma unroll
    for (int c = 0; c < COUT; c++)
#pragma unroll
        for (int q = 0; q < 4; q++) acc[c][q] = 0.f;

    float4 a0, a1, a2, b0, b1, b2;
    loadrows(a0, a1, a2, chan, o0, o1, o2);
    for (int ci = 0; ci < CH; ci += 2) {
        loadrows(b0, b1, b2, chan + HWP, o0, o1, o2);
        compute_ch(a0, a1, a2, wp + (size_t)ci * 9, acc, mt, mb, ml, mr);
        if (ci + 2 < CH)
            loadrows(a0, a1, a2, chan + 2 * HWP, o0, o1, o2);
        compute_ch(b0, b1, b2, wp + (size_t)(ci + 1) * 9, acc, mt, mb, ml, mr);
        chan += 2 * HWP;
    }

    const float scale = 1.0f / sqrtf((float)(CIN * 9));

    if (USE_WS) {
        float* dst = ws + ((size_t)(chunk * BATCH + b) * COUT) * HWP + (size_t)y * W + x0;
#pragma unroll
        for (int co = 0; co < COUT; co++)
            *(float4*)(dst + (size_t)co * HWP) =
                make_float4(acc[co][0] * scale, acc[co][1] * scale,
                            acc[co][2] * scale, acc[co][3] * scale);
    } else {
        float* outb = out + (size_t)b * COUT * HWP;
        int i0, i1; float wv0, wv1;
        if ((y & 1) == 0) { i0 = y >> 1;       wv0 = 0.75f; i1 = (y >> 1) - 1; wv1 = 0.25f; }
        else              { i0 = (y + 1) >> 1; wv0 = 0.25f; i1 = (y - 1) >> 1; wv1 = 0.75f; }
        const bool i0ok = (i0 >= 0 && i0 < 64), i1ok = (i1 >= 0 && i1 < 64);
#pragma unroll
        for (int q = 0; q < 4; q++) {
            int x = x0 + q;
            int j0, j1; float wh0, wh1;
            if ((x & 1) == 0) { j0 = x >> 1;       wh0 = 0.75f; j1 = (x >> 1) - 1; wh1 = 0.25f; }
            else              { j0 = (x + 1) >> 1; wh0 = 0.25f; j1 = (x - 1) >> 1; wh1 = 0.75f; }
            const bool j0ok = (j0 >= 0 && j0 < 64), j1ok = (j1 >= 0 && j1 < 64);
#pragma unroll
            for (int co = 0; co < COUT; co++) {
                float vv = acc[co][q] * scale;
                if (chunk == 0) {
                    const float* sk = skip + (size_t)(b * COUT + co) * 64 * 64;
                    float s00 = (i0ok && j0ok) ? sk[i0 * 64 + j0] : 0.f;
                    float s01 = (i0ok && j1ok) ? sk[i0 * 64 + j1] : 0.f;
                    float s10 = (i1ok && j0ok) ? sk[i1 * 64 + j0] : 0.f;
                    float s11 = (i1ok && j1ok) ? sk[i1 * 64 + j1] : 0.f;
                    vv += bias[co] + wv0 * (wh0 * s00 + wh1 * s01)
                                   + wv1 * (wh0 * s10 + wh1 * s11);
                }
                atomicAdd(&outb[(size_t)co * HWP + y * W + x], vv);
            }
        }
    }
}

// ---- reduction: out = sum_c ws[c]*1 + bias + upsampled skip ----
__global__ __launch_bounds__(256) void torgb_reduce(
    const float* __restrict__ ws, const float* __restrict__ skip,
    const float* __restrict__ bias, float* __restrict__ out)
{
    const int n4 = BATCH * COUT * HWP / 4;               // 98304
    int e4 = blockIdx.x * 256 + threadIdx.x;
    if (e4 >= n4) return;

    const int x4 = e4 & (W / 4 - 1);
    const int y  = (e4 >> 5) & (H - 1);
    const int co = (e4 >> 12) % COUT;
    const int b  = e4 / (COUT * H * W / 4);
    const int x0 = x4 * 4;

    float4 sum = make_float4(0.f, 0.f, 0.f, 0.f);
#pragma unroll
    for (int c = 0; c < CSPLIT; c++) {
        const float4 v = *(const float4*)&ws[((((size_t)c * BATCH + b) * COUT + co) * H + y) * W + x0];
        sum.x += v.x; sum.y += v.y; sum.z += v.z; sum.w += v.w;
    }

    int i0, i1; float wv0, wv1;
    if ((y & 1) == 0) { i0 = y >> 1;       wv0 = 0.75f; i1 = (y >> 1) - 1; wv1 = 0.25f; }
    else              { i0 = (y + 1) >> 1; wv0 = 0.25f; i1 = (y - 1) >> 1; wv1 = 0.75f; }
    const bool i0ok = (i0 >= 0 && i0 < 64), i1ok = (i1 >= 0 && i1 < 64);
    const float* sk = skip + (size_t)(b * COUT + co) * 64 * 64;
    const float bi = bias[co];

    float r[4] = {sum.x, sum.y, sum.z, sum.w};
#pragma unroll
    for (int q = 0; q < 4; q++) {
        int x = x0 + q;
        int j0, j1; float wh0, wh1;
        if ((x & 1) == 0) { j0 = x >> 1;       wh0 = 0.75f; j1 = (x >> 1) - 1; wh1 = 0.25f; }
        else              { j0 = (x + 1) >> 1; wh0 = 0.25f; j1 = (x - 1) >> 1; wh1 = 0.75f; }
        const bool j0ok = (j0 >= 0 && j0 < 64), j1ok = (j1 >= 0 && j1 < 64);
        float s00 = (i0ok && j0ok) ? sk[i0 * 64 + j0] : 0.f;
        float s01 = (i0ok && j1ok) ? sk[i0 * 64 + j1] : 0.f;
        float s10 = (i1ok && j0ok) ? sk[i1 * 64 + j0] : 0.f;
        float s11 = (i1ok && j1ok) ? sk[i1 * 64 + j1] : 0.f;
        r[q] += bi + wv0 * (wh0 * s00 + wh1 * s01) + wv1 * (wh0 * s10 + wh1 * s11);
    }
    *(float4*)&out[(size_t)e4 * 4] = make_float4(r[0], r[1], r[2], r[3]);
}

extern "C" void kernel_launch(void* const* d_in, const int* in_sizes, int n_in,
                              void* d_out, int out_size, void* d_ws, size_t ws_size,
                              hipStream_t stream) {
    const float* in     = (const float*)d_in[0];
    const float* skip   = (const float*)d_in[1];
    const float* weight = (const float*)d_in[2];
    const float* bias   = (const float*)d_in[3];
    float* out = (float*)d_out;
    float* ws  = (float*)d_ws;

    const size_t ws_needed = (size_t)CSPLIT * BATCH * COUT * HWP * sizeof(float);
    const dim3 grid(CSPLIT * BATCH * YTILES);   // 2048 blocks

    if (ws_size >= ws_needed) {
        torgb_conv<true><<<grid, 256, 0, stream>>>(in, skip, weight, bias, out, ws);
        const int n4 = BATCH * COUT * HWP / 4;
        torgb_reduce<<<(n4 + 255) / 256, 256, 0, stream>>>(ws, skip, bias, out);
    } else {
        hipMemsetAsync(out, 0, (size_t)out_size * sizeof(float), stream);
        torgb_conv<false><<<grid, 256, 0, stream>>>(in, skip, weight, bias, out, ws);
    }
}